// Round 4
// baseline (979.450 us; speedup 1.0000x reference)
//
#include <hip/hip_runtime.h>

typedef float f32x4 __attribute__((ext_vector_type(4)));
typedef __bf16 bf16x8 __attribute__((ext_vector_type(8)));
typedef unsigned short u16x8 __attribute__((ext_vector_type(8)));

#define F 128

__device__ __forceinline__ unsigned short bf16_rne(float f) {
  unsigned u = __float_as_uint(f);
  u += 0x7FFFu + ((u >> 16) & 1u);
  return (unsigned short)(u >> 16);
}
__device__ __forceinline__ float bf16f(unsigned short s) {
  return __uint_as_float((unsigned)s << 16);
}

// Activation layout is K-PLANED: arr[plane=k/32][node][32] as u16.
// Weight layout is PHASE-PACKED: per layer, 8 phases (ks 0..3 x col-half 0..1),
// each phase = 12 coltiles x 4 arrays {Wc_hi, Wc_lo, Whh_hi, Whh_lo} x 1KB frag.
// Fragment: byte = lane*16 + e*2 holds B[ct*16 + (lane&15)][ks*32 + (lane>>4)*8 + e].

// ---------------------------------------------------------------------------
// split8: x (f32, row-major) -> k-planed bf16 hi/lo planes
// ---------------------------------------------------------------------------
__global__ void split8_kernel(const float* __restrict__ in,
                              unsigned short* __restrict__ hi, unsigned short* __restrict__ lo,
                              int N) {
  int i = blockIdx.x * 256 + threadIdx.x;  // over N*16
  if (i >= N * 16) return;
  int node = i >> 4, f8 = i & 15;
  const float4* p = (const float4*)(in + (size_t)node * F + f8 * 8);
  float4 a = p[0], b = p[1];
  float v[8] = {a.x, a.y, a.z, a.w, b.x, b.y, b.z, b.w};
  u16x8 vh, vl;
#pragma unroll
  for (int e = 0; e < 8; ++e) {
    unsigned short x = bf16_rne(v[e]);
    vh[e] = x;
    vl[e] = bf16_rne(v[e] - bf16f(x));
  }
  size_t o = ((size_t)(f8 >> 2) * N + node) * 32 + (f8 & 3) * 8;
  *(u16x8*)(hi + o) = vh;
  *(u16x8*)(lo + o) = vl;
}

// ---------------------------------------------------------------------------
// prep_w: phase-packed combined weights.
//   Wc[t][j][k] = dot(W[t][k][:], w_ih[j][:]);  Whh[j][k] = w_hh[j][k]
// ---------------------------------------------------------------------------
__global__ void prep_w_kernel(const float* __restrict__ W, const float* __restrict__ w_ih,
                              const float* __restrict__ w_hh,
                              unsigned short* __restrict__ Bpack, int L) {
  int idx = blockIdx.x * 256 + threadIdx.x;
  if (idx >= L * 8 * 12 * 2 * 512) return;
  int low = idx & 511;
  int e = low & 7, lane = low >> 3;
  int rest = idx >> 9;
  int ap = rest & 1; rest >>= 1;
  int ct = rest % 12; rest /= 12;
  int ph = rest & 7, t = rest >> 3;
  int j = (ph & 1) * 192 + ct * 16 + (lane & 15);
  int k = (ph >> 1) * 32 + (lane >> 4) * 8 + e;
  float v;
  if (ap == 0) {
    const float* wi = w_ih + (size_t)j * 128;
    const float* wk = W + (size_t)t * 16384 + (size_t)k * 128;
    float acc = 0.f;
#pragma unroll 4
    for (int c = 0; c < 128; ++c) acc = fmaf(wk[c], wi[c], acc);
    v = acc;
  } else {
    v = w_hh[(size_t)j * 128 + k];
  }
  unsigned short x = bf16_rne(v);
  size_t base = (size_t)t * 196608 + (size_t)((ph * 12 + ct) * 4 + ap * 2) * 512 + lane * 8 + e;
  Bpack[base] = x;
  Bpack[base + 512] = bf16_rne(v - bf16f(x));
}

// ---------------------------------------------------------------------------
// CSR build
// ---------------------------------------------------------------------------
__global__ void hist_kernel(const int* __restrict__ ei, int* __restrict__ cnt, int E) {
  int e = blockIdx.x * 256 + threadIdx.x;
  if (e < E) atomicAdd(&cnt[ei[E + e]], 1);
}

__global__ void scan1_kernel(const int* __restrict__ cnt, int* __restrict__ exscan,
                             int* __restrict__ chunk_sums, int N) {
  __shared__ int tmp[256];
  int i = blockIdx.x * 256 + threadIdx.x;
  int v = (i < N) ? cnt[i] : 0;
  tmp[threadIdx.x] = v;
  __syncthreads();
#pragma unroll
  for (int off = 1; off < 256; off <<= 1) {
    int a = (threadIdx.x >= off) ? tmp[threadIdx.x - off] : 0;
    __syncthreads();
    tmp[threadIdx.x] += a;
    __syncthreads();
  }
  if (i < N) exscan[i] = tmp[threadIdx.x] - v;
  if (threadIdx.x == 255) chunk_sums[blockIdx.x] = tmp[255];
}

__global__ void scan2_kernel(int* __restrict__ chunk_sums, int nchunk) {
  __shared__ int tmp[256];
  int v = (threadIdx.x < nchunk) ? chunk_sums[threadIdx.x] : 0;
  tmp[threadIdx.x] = v;
  __syncthreads();
#pragma unroll
  for (int off = 1; off < 256; off <<= 1) {
    int a = (threadIdx.x >= off) ? tmp[threadIdx.x - off] : 0;
    __syncthreads();
    tmp[threadIdx.x] += a;
    __syncthreads();
  }
  if (threadIdx.x < nchunk) chunk_sums[threadIdx.x] = tmp[threadIdx.x] - v;
}

__global__ void finalize_rowptr_kernel(const int* __restrict__ exscan,
                                       const int* __restrict__ chunk_sums,
                                       int* __restrict__ rowptr, int* __restrict__ cursor,
                                       int N, int E) {
  int i = blockIdx.x * 256 + threadIdx.x;
  if (i < N) {
    int v = exscan[i] + chunk_sums[i >> 8];
    rowptr[i] = v;
    cursor[i] = v;
  }
  if (i == N) rowptr[N] = E;
}

__global__ void place_kernel(const int* __restrict__ ei, int* __restrict__ cursor,
                             int* __restrict__ csr_src, int E) {
  int e = blockIdx.x * 256 + threadIdx.x;
  if (e >= E) return;
  int pos = atomicAdd(&cursor[ei[E + e]], 1);
  csr_src[pos] = ei[e];
}

// ---------------------------------------------------------------------------
// gather (k-planed I/O), 64 threads/node
// ---------------------------------------------------------------------------
__global__ __launch_bounds__(256) void gather_kernel(
    const unsigned* __restrict__ hh, const unsigned* __restrict__ hl,
    const int* __restrict__ rowptr, const int* __restrict__ csr_src,
    unsigned* __restrict__ shi, unsigned* __restrict__ slo, int N) {
  int node = blockIdx.x * 4 + (threadIdx.x >> 6);
  if (node >= N) return;
  int d = threadIdx.x & 63;
  const size_t pb = (size_t)(d >> 4) * N * 16 + (d & 15);
  int j = rowptr[node], end = rowptr[node + 1];
  float a0 = 0.f, a1 = 0.f;
  for (; j + 8 <= end; j += 8) {
#pragma unroll
    for (int u = 0; u < 8; ++u) {
      int s = csr_src[j + u];
      unsigned hv = hh[pb + (size_t)s * 16];
      unsigned lv = hl[pb + (size_t)s * 16];
      a0 += bf16f((unsigned short)(hv & 0xffff)) + bf16f((unsigned short)(lv & 0xffff));
      a1 += bf16f((unsigned short)(hv >> 16)) + bf16f((unsigned short)(lv >> 16));
    }
  }
  for (; j + 4 <= end; j += 4) {
#pragma unroll
    for (int u = 0; u < 4; ++u) {
      int s = csr_src[j + u];
      unsigned hv = hh[pb + (size_t)s * 16];
      unsigned lv = hl[pb + (size_t)s * 16];
      a0 += bf16f((unsigned short)(hv & 0xffff)) + bf16f((unsigned short)(lv & 0xffff));
      a1 += bf16f((unsigned short)(hv >> 16)) + bf16f((unsigned short)(lv >> 16));
    }
  }
  for (; j < end; ++j) {
    int s = csr_src[j];
    unsigned hv = hh[pb + (size_t)s * 16];
    unsigned lv = hl[pb + (size_t)s * 16];
    a0 += bf16f((unsigned short)(hv & 0xffff)) + bf16f((unsigned short)(lv & 0xffff));
    a1 += bf16f((unsigned short)(hv >> 16)) + bf16f((unsigned short)(lv >> 16));
  }
  unsigned short x0 = bf16_rne(a0), x1 = bf16_rne(a1);
  unsigned short y0 = bf16_rne(a0 - bf16f(x0)), y1 = bf16_rne(a1 - bf16f(x1));
  shi[pb + (size_t)node * 16] = (unsigned)x0 | ((unsigned)x1 << 16);
  slo[pb + (size_t)node * 16] = (unsigned)y0 | ((unsigned)y1 << 16);
}

// ---------------------------------------------------------------------------
// gemm_gru: 8-phase LDS pipeline (see header comment in theory)
// ---------------------------------------------------------------------------
#define BBUF(b) ((b) * 49152)
#define ABUF 98304

__device__ __forceinline__ void g2l(const void* g, void* l) {
  __builtin_amdgcn_global_load_lds((const __attribute__((address_space(1))) void*)g,
                                   (__attribute__((address_space(3))) void*)l, 16, 0, 0);
}

#define DS_READ_A()                                                                  \
  {                                                                                  \
    _Pragma("unroll") for (int t = 0; t < 2; ++t) {                                  \
      int row = rh * 32 + t * 16 + lrow;                                             \
      const unsigned char* ab = lds + ABUF + row * 64 + ((kq ^ (row & 3)) << 4);     \
      ash[t] = *(const bf16x8*)(ab);                                                 \
      asl[t] = *(const bf16x8*)(ab + 4096);                                          \
      ahh[t] = *(const bf16x8*)(ab + 8192);                                          \
      ahl[t] = *(const bf16x8*)(ab + 12288);                                         \
    }                                                                                \
  }

#define DS_READ_B(bb)                                                                \
  bf16x8 bch[3], bcl[3], bh2[3], bhl[3];                                             \
  {                                                                                  \
    _Pragma("unroll") for (int jj = 0; jj < 3; ++jj) {                               \
      const unsigned char* bp = lds + BBUF(bb) + (q + jj * 4) * 4096 + lane * 16;    \
      bch[jj] = *(const bf16x8*)(bp);                                                \
      bcl[jj] = *(const bf16x8*)(bp + 1024);                                         \
      bh2[jj] = *(const bf16x8*)(bp + 2048);                                         \
      bhl[jj] = *(const bf16x8*)(bp + 3072);                                         \
    }                                                                                \
  }

#define MFMA_BLOCK(half)                                                             \
  {                                                                                  \
    const int PT[2][3] = {{0, 0, 1}, {1, 2, 2}};                                     \
    const int FG[2][3] = {{0, 1, 0}, {1, 0, 1}};                                     \
    _Pragma("unroll") for (int jj = 0; jj < 3; ++jj) {                               \
      const int part = PT[half][jj], fgi = FG[half][jj];                             \
      _Pragma("unroll") for (int t = 0; t < 2; ++t) {                                \
        const int ai = ((t * 2 + fgi) * 3 + part) * 2;                               \
        acc[ai] = __builtin_amdgcn_mfma_f32_16x16x32_bf16(ash[t], bch[jj], acc[ai], 0, 0, 0); \
        acc[ai] = __builtin_amdgcn_mfma_f32_16x16x32_bf16(asl[t], bch[jj], acc[ai], 0, 0, 0); \
        acc[ai] = __builtin_amdgcn_mfma_f32_16x16x32_bf16(ash[t], bcl[jj], acc[ai], 0, 0, 0); \
        acc[ai + 1] = __builtin_amdgcn_mfma_f32_16x16x32_bf16(ahh[t], bh2[jj], acc[ai + 1], 0, 0, 0); \
        acc[ai + 1] = __builtin_amdgcn_mfma_f32_16x16x32_bf16(ahl[t], bh2[jj], acc[ai + 1], 0, 0, 0); \
        acc[ai + 1] = __builtin_amdgcn_mfma_f32_16x16x32_bf16(ahh[t], bhl[jj], acc[ai + 1], 0, 0, 0); \
      }                                                                              \
    }                                                                                \
  }

#define WAIT_LGKM()                                                                  \
  asm volatile("s_waitcnt lgkmcnt(0)" ::: "memory");                                 \
  __builtin_amdgcn_sched_barrier(0);

__global__ __launch_bounds__(512, 1) void gemm_gru_kernel(
    const unsigned short* s_hi, const unsigned short* s_lo,
    const unsigned short* h_hi, const unsigned short* h_lo,
    const unsigned short* __restrict__ Bpack,
    const float* __restrict__ bih, const float* __restrict__ bhh,
    unsigned short* h_hi_out, unsigned short* h_lo_out, int N) {
  __shared__ __align__(1024) unsigned char lds[114688];
  const int tid = threadIdx.x, w = tid >> 6, lane = tid & 63;
  const int q = w & 3, rh = w >> 2, lrow = lane & 15, kq = lane >> 4;
  const int row0 = blockIdx.x * 64;

  auto stageB = [&](int ph, int b) {
    const unsigned char* g = (const unsigned char*)Bpack + (size_t)ph * 49152 + w * 6144 + lane * 16;
    unsigned char* l = lds + BBUF(b) + w * 6144;
#pragma unroll
    for (int i = 0; i < 6; ++i) g2l(g + i * 1024, l + i * 1024);
  };
  auto stageA = [&](int ks) {
    const int arr = w >> 1;
    const unsigned short* ap = (arr == 0) ? s_hi : (arr == 1) ? s_lo : (arr == 2) ? h_hi : h_lo;
    const int slot = (lane & 3) ^ ((lane >> 2) & 3);
    unsigned char* l = lds + ABUF + arr * 4096;
#pragma unroll
    for (int i = 0; i < 2; ++i) {
      const int chunk = (w & 1) * 2 + i;
      int gr = row0 + chunk * 16 + (lane >> 2);
      if (gr >= N) gr = N - 1;
      const unsigned char* g = (const unsigned char*)ap + ((size_t)ks * N + gr) * 64 + slot * 16;
      g2l(g, l + chunk * 1024);
    }
  };

  f32x4 acc[24];
#pragma unroll
  for (int i = 0; i < 24; ++i) acc[i] = (f32x4){0.f, 0.f, 0.f, 0.f};
  bf16x8 ash[2], asl[2], ahh[2], ahl[2];

  stageB(0, 0);
  stageA(0);
  stageB(1, 1);
  asm volatile("s_waitcnt vmcnt(6)" ::: "memory");
  __builtin_amdgcn_s_barrier();

  {  // phase 0
    DS_READ_A();
    DS_READ_B(0);
    WAIT_LGKM();
    __builtin_amdgcn_s_barrier();
    stageB(2, 0);
    stageA(1);
    __builtin_amdgcn_s_setprio(1);
    MFMA_BLOCK(0);
    __builtin_amdgcn_s_setprio(0);
    asm volatile("s_waitcnt vmcnt(8)" ::: "memory");
    __builtin_amdgcn_s_barrier();
  }
  {  // phase 1
    DS_READ_B(1);
    WAIT_LGKM();
    __builtin_amdgcn_s_barrier();
    stageB(3, 1);
    __builtin_amdgcn_s_setprio(1);
    MFMA_BLOCK(1);
    __builtin_amdgcn_s_setprio(0);
    asm volatile("s_waitcnt vmcnt(6)" ::: "memory");
    __builtin_amdgcn_s_barrier();
  }
  {  // phase 2
    DS_READ_A();
    DS_READ_B(0);
    WAIT_LGKM();
    __builtin_amdgcn_s_barrier();
    stageB(4, 0);
    stageA(2);
    __builtin_amdgcn_s_setprio(1);
    MFMA_BLOCK(0);
    __builtin_amdgcn_s_setprio(0);
    asm volatile("s_waitcnt vmcnt(8)" ::: "memory");
    __builtin_amdgcn_s_barrier();
  }
  {  // phase 3
    DS_READ_B(1);
    WAIT_LGKM();
    __builtin_amdgcn_s_barrier();
    stageB(5, 1);
    __builtin_amdgcn_s_setprio(1);
    MFMA_BLOCK(1);
    __builtin_amdgcn_s_setprio(0);
    asm volatile("s_waitcnt vmcnt(6)" ::: "memory");
    __builtin_amdgcn_s_barrier();
  }
  {  // phase 4
    DS_READ_A();
    DS_READ_B(0);
    WAIT_LGKM();
    __builtin_amdgcn_s_barrier();
    stageB(6, 0);
    stageA(3);
    __builtin_amdgcn_s_setprio(1);
    MFMA_BLOCK(0);
    __builtin_amdgcn_s_setprio(0);
    asm volatile("s_waitcnt vmcnt(8)" ::: "memory");
    __builtin_amdgcn_s_barrier();
  }
  {  // phase 5
    DS_READ_B(1);
    WAIT_LGKM();
    __builtin_amdgcn_s_barrier();
    stageB(7, 1);
    __builtin_amdgcn_s_setprio(1);
    MFMA_BLOCK(1);
    __builtin_amdgcn_s_setprio(0);
    asm volatile("s_waitcnt vmcnt(6)" ::: "memory");
    __builtin_amdgcn_s_barrier();
  }
  {  // phase 6
    DS_READ_A();
    DS_READ_B(0);
    WAIT_LGKM();
    __builtin_amdgcn_s_barrier();
    __builtin_amdgcn_s_setprio(1);
    MFMA_BLOCK(0);
    __builtin_amdgcn_s_setprio(0);
    asm volatile("s_waitcnt vmcnt(0)" ::: "memory");
    __builtin_amdgcn_s_barrier();
  }
  {  // phase 7
    DS_READ_B(1);
    __builtin_amdgcn_s_setprio(1);
    MFMA_BLOCK(1);
    __builtin_amdgcn_s_setprio(0);
  }

#pragma unroll
  for (int t = 0; t < 2; ++t) {
    const int rb = row0 + rh * 32 + t * 16 + kq * 4;
#pragma unroll
    for (int fi = 0; fi < 2; ++fi) {
      const int fg = q + fi * 4;
      const int c = fg * 16 + lrow;
      const float br = bih[c] + bhh[c];
      const float bz = bih[128 + c] + bhh[128 + c];
      const float bni = bih[256 + c], bnh = bhh[256 + c];
#pragma unroll
      for (int i = 0; i < 4; ++i) {
        const int r = rb + i;
        if (r < N) {
          const int a0 = ((t * 2 + fi) * 3) * 2;
          const float c1r = acc[a0 + 0][i], c2r = acc[a0 + 1][i];
          const float c1z = acc[a0 + 2][i], c2z = acc[a0 + 3][i];
          const float c1n = acc[a0 + 4][i], c2n = acc[a0 + 5][i];
          const float rr = 1.f / (1.f + __expf(-(c1r + c2r + br)));
          const float zz = 1.f / (1.f + __expf(-(c1z + c2z + bz)));
          const float nn = tanhf(c1n + bni + rr * (c2n + bnh));
          const size_t o = ((size_t)(fg >> 1) * N + r) * 32 + (fg & 1) * 16 + lrow;
          const float hold = bf16f(h_hi_out[o]) + bf16f(h_lo_out[o]);
          const float hn = (1.f - zz) * nn + zz * hold;
          const unsigned short x = bf16_rne(hn);
          h_hi_out[o] = x;
          h_lo_out[o] = bf16_rne(hn - bf16f(x));
        }
      }
    }
  }
}

// ---------------------------------------------------------------------------
// final: out[n] = relu(h[n]) . lin_w + lin_b
// ---------------------------------------------------------------------------
__global__ void final_kernel(const unsigned* __restrict__ hh, const unsigned* __restrict__ hl,
                             const float* __restrict__ lin_w,
                             const float* __restrict__ lin_b, float* __restrict__ out, int N) {
  int n = blockIdx.x * 4 + (threadIdx.x >> 6);
  if (n >= N) return;
  int d = threadIdx.x & 63;
  size_t o = ((size_t)(d >> 4) * N + n) * 16 + (d & 15);
  unsigned wh = hh[o], wl = hl[o];
  float v0 = bf16f((unsigned short)(wh & 0xffff)) + bf16f((unsigned short)(wl & 0xffff));
  float v1 = bf16f((unsigned short)(wh >> 16)) + bf16f((unsigned short)(wl >> 16));
  int f0 = (d >> 4) * 32 + 2 * (d & 15);
  float sum = fmaxf(v0, 0.f) * lin_w[f0] + fmaxf(v1, 0.f) * lin_w[f0 + 1];
#pragma unroll
  for (int s = 32; s; s >>= 1) sum += __shfl_xor(sum, s, 64);
  if (d == 0) out[n] = sum + lin_b[0];
}

// ---------------------------------------------------------------------------
extern "C" void kernel_launch(void* const* d_in, const int* in_sizes, int n_in,
                              void* d_out, int out_size, void* d_ws, size_t ws_size,
                              hipStream_t stream) {
  const float* x     = (const float*)d_in[0];
  const int*   ei    = (const int*)d_in[1];
  const float* W     = (const float*)d_in[2];
  const float* w_ih  = (const float*)d_in[3];
  const float* w_hh  = (const float*)d_in[4];
  const float* b_ih  = (const float*)d_in[5];
  const float* b_hh  = (const float*)d_in[6];
  const float* lin_w = (const float*)d_in[7];
  const float* lin_b = (const float*)d_in[8];

  const int N = in_sizes[0] / F;
  const int E = in_sizes[1] / 2;
  const int L = in_sizes[2] / (F * F);
  const size_t NF = (size_t)N * F;

  char* p = (char*)d_ws;
  unsigned short* h_hi = (unsigned short*)p; p += NF * 2;
  unsigned short* h_lo = (unsigned short*)p; p += NF * 2;
  unsigned short* s_hi = (unsigned short*)p; p += NF * 2;
  unsigned short* s_lo = (unsigned short*)p; p += NF * 2;
  unsigned short* Bpack = (unsigned short*)p; p += (size_t)L * 196608 * 2;
  int* cnt     = (int*)p; p += (size_t)N * 4;
  int* exscan  = (int*)p; p += (size_t)N * 4;
  int* chunk   = (int*)p; p += 256 * 4;
  int* rowptr  = (int*)p; p += ((size_t)N + 1) * 4;
  int* cursor  = (int*)p; p += (size_t)N * 4;
  int* csr_src = (int*)p; p += (size_t)E * 4;

  const int split_blocks = (N * 16 + 255) / 256;
  const int prep_blocks = (L * 8 * 12 * 2 * 512 + 255) / 256;
  const int edge_blocks = (E + 255) / 256;
  const int nchunk = (N + 255) / 256;
  const int gemm_blocks = (N + 63) / 64;
  const int node4_blocks = (N + 3) / 4;

  split8_kernel<<<split_blocks, 256, 0, stream>>>(x, h_hi, h_lo, N);
  prep_w_kernel<<<prep_blocks, 256, 0, stream>>>(W, w_ih, w_hh, Bpack, L);

  hipMemsetAsync(cnt, 0, (size_t)N * 4, stream);
  hist_kernel<<<edge_blocks, 256, 0, stream>>>(ei, cnt, E);
  scan1_kernel<<<nchunk, 256, 0, stream>>>(cnt, exscan, chunk, N);
  scan2_kernel<<<1, 256, 0, stream>>>(chunk, nchunk);
  finalize_rowptr_kernel<<<(N + 256) / 256, 256, 0, stream>>>(exscan, chunk, rowptr, cursor, N, E);
  place_kernel<<<edge_blocks, 256, 0, stream>>>(ei, cursor, csr_src, E);

  for (int t = 0; t < L; ++t) {
    gather_kernel<<<node4_blocks, 256, 0, stream>>>(
        (const unsigned*)h_hi, (const unsigned*)h_lo, rowptr, csr_src,
        (unsigned*)s_hi, (unsigned*)s_lo, N);
    gemm_gru_kernel<<<gemm_blocks, 512, 0, stream>>>(
        s_hi, s_lo, h_hi, h_lo, Bpack + (size_t)t * 196608,
        b_ih, b_hh, h_hi, h_lo, N);
  }

  final_kernel<<<node4_blocks, 256, 0, stream>>>(
      (const unsigned*)h_hi, (const unsigned*)h_lo, lin_w, lin_b, (float*)d_out, N);
}

// Round 5
// 848.181 us; speedup vs baseline: 1.1548x; 1.1548x over previous
//
#include <hip/hip_runtime.h>

typedef float f32x4 __attribute__((ext_vector_type(4)));
typedef __bf16 bf16x8 __attribute__((ext_vector_type(8)));
typedef unsigned short u16x8 __attribute__((ext_vector_type(8)));

#define F 128

__device__ __forceinline__ unsigned short bf16_rne(float f) {
  unsigned u = __float_as_uint(f);
  u += 0x7FFFu + ((u >> 16) & 1u);
  return (unsigned short)(u >> 16);
}
__device__ __forceinline__ float bf16f(unsigned short s) {
  return __uint_as_float((unsigned)s << 16);
}

// Activation layout K-PLANED: arr[plane=k/32][node][32] u16.
// Weight layout FRAG-PACKED: per layer, frag ff = ((ks*2+g)*8 + w)*3 + part,
// storage [ff][hi 1KB][lo 1KB]; frag byte l*16+e*2 holds
// B[part*128 + w*16 + (l&15)][ks*32 + (l>>4)*8 + e].  g=0: Wc, g=1: Whh.

// ---------------------------------------------------------------------------
// split8: x (f32, row-major) -> k-planed bf16 hi/lo planes
// ---------------------------------------------------------------------------
__global__ void split8_kernel(const float* __restrict__ in,
                              unsigned short* __restrict__ hi, unsigned short* __restrict__ lo,
                              int N) {
  int i = blockIdx.x * 256 + threadIdx.x;  // over N*16
  if (i >= N * 16) return;
  int node = i >> 4, f8 = i & 15;
  const float4* p = (const float4*)(in + (size_t)node * F + f8 * 8);
  float4 a = p[0], b = p[1];
  float v[8] = {a.x, a.y, a.z, a.w, b.x, b.y, b.z, b.w};
  u16x8 vh, vl;
#pragma unroll
  for (int e = 0; e < 8; ++e) {
    unsigned short x = bf16_rne(v[e]);
    vh[e] = x;
    vl[e] = bf16_rne(v[e] - bf16f(x));
  }
  size_t o = ((size_t)(f8 >> 2) * N + node) * 32 + (f8 & 3) * 8;
  *(u16x8*)(hi + o) = vh;
  *(u16x8*)(lo + o) = vl;
}

// ---------------------------------------------------------------------------
// prep_w: frag-packed combined weights.
//   Wc[t][j][k] = dot(W[t][k][:], w_ih[j][:]);  Whh[j][k] = w_hh[j][k]
// ---------------------------------------------------------------------------
__global__ void prep_w_kernel(const float* __restrict__ W, const float* __restrict__ w_ih,
                              const float* __restrict__ w_hh,
                              unsigned short* __restrict__ Bpack, int L) {
  int idx = blockIdx.x * 256 + threadIdx.x;
  if (idx >= L * 98304) return;
  int e = idx & 7;
  int l = (idx >> 3) & 63;
  int fp = idx >> 9;            // frag-value group: L*192
  int part = fp % 3;
  int rest = fp / 3;            // L*64
  int w = rest & 7, g = (rest >> 3) & 1, ks = (rest >> 4) & 3, t = rest >> 6;
  int j = part * 128 + w * 16 + (l & 15);
  int k = ks * 32 + ((l >> 4) & 3) * 8 + e;
  float v;
  if (g == 0) {
    const float* wi = w_ih + (size_t)j * 128;
    const float* wk = W + (size_t)t * 16384 + (size_t)k * 128;
    float acc = 0.f;
#pragma unroll 4
    for (int c = 0; c < 128; ++c) acc = fmaf(wk[c], wi[c], acc);
    v = acc;
  } else {
    v = w_hh[(size_t)j * 128 + k];
  }
  int ff = ((ks * 2 + g) * 8 + w) * 3 + part;
  size_t base = (size_t)t * 196608 + (size_t)ff * 1024 + l * 8 + e;
  unsigned short x = bf16_rne(v);
  Bpack[base] = x;
  Bpack[base + 512] = bf16_rne(v - bf16f(x));
}

// ---------------------------------------------------------------------------
// CSR build
// ---------------------------------------------------------------------------
__global__ void hist_kernel(const int* __restrict__ ei, int* __restrict__ cnt, int E) {
  int e = blockIdx.x * 256 + threadIdx.x;
  if (e < E) atomicAdd(&cnt[ei[E + e]], 1);
}

__global__ void scan1_kernel(const int* __restrict__ cnt, int* __restrict__ exscan,
                             int* __restrict__ chunk_sums, int N) {
  __shared__ int tmp[256];
  int i = blockIdx.x * 256 + threadIdx.x;
  int v = (i < N) ? cnt[i] : 0;
  tmp[threadIdx.x] = v;
  __syncthreads();
#pragma unroll
  for (int off = 1; off < 256; off <<= 1) {
    int a = (threadIdx.x >= off) ? tmp[threadIdx.x - off] : 0;
    __syncthreads();
    tmp[threadIdx.x] += a;
    __syncthreads();
  }
  if (i < N) exscan[i] = tmp[threadIdx.x] - v;
  if (threadIdx.x == 255) chunk_sums[blockIdx.x] = tmp[255];
}

__global__ void scan2_kernel(int* __restrict__ chunk_sums, int nchunk) {
  __shared__ int tmp[256];
  int v = (threadIdx.x < nchunk) ? chunk_sums[threadIdx.x] : 0;
  tmp[threadIdx.x] = v;
  __syncthreads();
#pragma unroll
  for (int off = 1; off < 256; off <<= 1) {
    int a = (threadIdx.x >= off) ? tmp[threadIdx.x - off] : 0;
    __syncthreads();
    tmp[threadIdx.x] += a;
    __syncthreads();
  }
  if (threadIdx.x < nchunk) chunk_sums[threadIdx.x] = tmp[threadIdx.x] - v;
}

__global__ void finalize_rowptr_kernel(const int* __restrict__ exscan,
                                       const int* __restrict__ chunk_sums,
                                       int* __restrict__ rowptr, int* __restrict__ cursor,
                                       int N, int E) {
  int i = blockIdx.x * 256 + threadIdx.x;
  if (i < N) {
    int v = exscan[i] + chunk_sums[i >> 8];
    rowptr[i] = v;
    cursor[i] = v;
  }
  if (i == N) rowptr[N] = E;
}

__global__ void place_kernel(const int* __restrict__ ei, int* __restrict__ cursor,
                             int* __restrict__ csr_src, int E) {
  int e = blockIdx.x * 256 + threadIdx.x;
  if (e >= E) return;
  int pos = atomicAdd(&cursor[ei[E + e]], 1);
  csr_src[pos] = ei[e];
}

// ---------------------------------------------------------------------------
// gather (k-planed I/O), 64 threads/node
// ---------------------------------------------------------------------------
__global__ __launch_bounds__(256) void gather_kernel(
    const unsigned* __restrict__ hh, const unsigned* __restrict__ hl,
    const int* __restrict__ rowptr, const int* __restrict__ csr_src,
    unsigned* __restrict__ shi, unsigned* __restrict__ slo, int N) {
  int node = blockIdx.x * 4 + (threadIdx.x >> 6);
  if (node >= N) return;
  int d = threadIdx.x & 63;
  const size_t pb = (size_t)(d >> 4) * N * 16 + (d & 15);
  int j = rowptr[node], end = rowptr[node + 1];
  float a0 = 0.f, a1 = 0.f;
  for (; j + 8 <= end; j += 8) {
#pragma unroll
    for (int u = 0; u < 8; ++u) {
      int s = csr_src[j + u];
      unsigned hv = hh[pb + (size_t)s * 16];
      unsigned lv = hl[pb + (size_t)s * 16];
      a0 += bf16f((unsigned short)(hv & 0xffff)) + bf16f((unsigned short)(lv & 0xffff));
      a1 += bf16f((unsigned short)(hv >> 16)) + bf16f((unsigned short)(lv >> 16));
    }
  }
  for (; j + 4 <= end; j += 4) {
#pragma unroll
    for (int u = 0; u < 4; ++u) {
      int s = csr_src[j + u];
      unsigned hv = hh[pb + (size_t)s * 16];
      unsigned lv = hl[pb + (size_t)s * 16];
      a0 += bf16f((unsigned short)(hv & 0xffff)) + bf16f((unsigned short)(lv & 0xffff));
      a1 += bf16f((unsigned short)(hv >> 16)) + bf16f((unsigned short)(lv >> 16));
    }
  }
  for (; j < end; ++j) {
    int s = csr_src[j];
    unsigned hv = hh[pb + (size_t)s * 16];
    unsigned lv = hl[pb + (size_t)s * 16];
    a0 += bf16f((unsigned short)(hv & 0xffff)) + bf16f((unsigned short)(lv & 0xffff));
    a1 += bf16f((unsigned short)(hv >> 16)) + bf16f((unsigned short)(lv >> 16));
  }
  unsigned short x0 = bf16_rne(a0), x1 = bf16_rne(a1);
  unsigned short y0 = bf16_rne(a0 - bf16f(x0)), y1 = bf16_rne(a1 - bf16f(x1));
  shi[pb + (size_t)node * 16] = (unsigned)x0 | ((unsigned)x1 << 16);
  slo[pb + (size_t)node * 16] = (unsigned)y0 | ((unsigned)y1 << 16);
}

// ---------------------------------------------------------------------------
// gemm_gru: 64 rows x 384 gate-cols per block, 8 waves. Wave w owns feature
// tile w (16 features) = coltiles {r,z,n} for all 64 rows -> B loaded once
// per block (no duplication). A (s,h hi/lo, 4 ks-planes) staged once into
// 64KB LDS via global_load_lds; ONE barrier. K-loop: 8 half-steps
// hs = ks*2+g (g=0: s@Wc, g=1: h@Whh); 2-deep register double-buffer:
// while 36 MFMAs consume buf[hs&1], the 6 B-frags (global) + 8 A-frags
// (ds_read) of hs+1 fill buf[(hs+1)&1]. No per-phase barriers.
// ---------------------------------------------------------------------------
__device__ __forceinline__ void g2l(const void* g, void* l) {
  __builtin_amdgcn_global_load_lds((const __attribute__((address_space(1))) void*)g,
                                   (__attribute__((address_space(3))) void*)l, 16, 0, 0);
}

__global__ __launch_bounds__(512, 2) void gemm_gru_kernel(
    const unsigned short* __restrict__ s_hi, const unsigned short* __restrict__ s_lo,
    const unsigned short* __restrict__ h_hi, const unsigned short* __restrict__ h_lo,
    const unsigned short* __restrict__ Bpack,
    const float* __restrict__ bih, const float* __restrict__ bhh,
    unsigned short* h_hi_out, unsigned short* h_lo_out, int N) {
  __shared__ __align__(1024) unsigned char lds[65536];
  const int tid = threadIdx.x, w = tid >> 6, lane = tid & 63;
  const int lrow = lane & 15, kq = lane >> 4;
  const int row0 = blockIdx.x * 64;

  // ---- stage A: 64 x 1KB chunks; chunk ci = w*8 + i covers
  //      (array = ci>>4, ks = (ci>>2)&3, quarter = ci&3), rows quarter*16..+15
  {
    const int arr = w >> 1;  // wave-constant
    const unsigned short* ap = (arr == 0) ? s_hi : (arr == 1) ? s_lo : (arr == 2) ? h_hi : h_lo;
#pragma unroll
    for (int i = 0; i < 8; ++i) {
      const int ks = (2 * w + (i >> 2)) & 3;
      int r = row0 + (i & 3) * 16 + (lane >> 2);
      if (r >= N) r = N - 1;
      const unsigned short* g = ap + ((size_t)ks * N + r) * 32 + (lane & 3) * 8;
      g2l(g, lds + (w * 8 + i) * 1024 + (lane & 3) * 16 + ((lane >> 2) & 15) * 64);
    }
  }

  f32x4 acc[24];  // [(t*3+part)*2 + g]
#pragma unroll
  for (int i = 0; i < 24; ++i) acc[i] = (f32x4){0.f, 0.f, 0.f, 0.f};

  bf16x8 Bf[2][6];  // [buf][part*2 + hl]
  bf16x8 Af[2][8];  // [buf][t] = hi, [buf][4+t] = lo

  const unsigned char* Bbase = (const unsigned char*)Bpack + (size_t)w * 6144 + lane * 16;

  asm volatile("s_waitcnt vmcnt(0)" ::: "memory");
  __syncthreads();

#define LOADB(hs, buf)                                                           \
  {                                                                              \
    const unsigned char* bg = Bbase + (size_t)(hs) * 49152;                      \
    _Pragma("unroll") for (int i = 0; i < 6; ++i)                                \
        Bf[buf][i] = *(const bf16x8*)(bg + i * 1024);                            \
  }
#define LOADA(hs, buf)                                                           \
  {                                                                              \
    const int ks_ = (hs) >> 1, g_ = (hs) & 1;                                    \
    const unsigned char* bh = lds + ((g_ * 2) * 4 + ks_) * 4096 + lrow * 64 + kq * 16;      \
    const unsigned char* bl = lds + ((g_ * 2 + 1) * 4 + ks_) * 4096 + lrow * 64 + kq * 16;  \
    _Pragma("unroll") for (int t = 0; t < 4; ++t) {                              \
      Af[buf][t] = *(const bf16x8*)(bh + t * 1024);                              \
      Af[buf][4 + t] = *(const bf16x8*)(bl + t * 1024);                          \
    }                                                                            \
  }
#define DOMFMA(hs, buf)                                                          \
  {                                                                              \
    const int g_ = (hs) & 1;                                                     \
    _Pragma("unroll") for (int part = 0; part < 3; ++part)                       \
        _Pragma("unroll") for (int t = 0; t < 4; ++t) {                          \
      const int ai = (t * 3 + part) * 2 + g_;                                    \
      acc[ai] = __builtin_amdgcn_mfma_f32_16x16x32_bf16(Af[buf][t], Bf[buf][part * 2], acc[ai], 0, 0, 0);     \
      acc[ai] = __builtin_amdgcn_mfma_f32_16x16x32_bf16(Af[buf][4 + t], Bf[buf][part * 2], acc[ai], 0, 0, 0); \
      acc[ai] = __builtin_amdgcn_mfma_f32_16x16x32_bf16(Af[buf][t], Bf[buf][part * 2 + 1], acc[ai], 0, 0, 0); \
    }                                                                            \
  }

  LOADB(0, 0);
  LOADA(0, 0);
#pragma unroll
  for (int hs = 0; hs < 8; ++hs) {
    if (hs < 7) {
      LOADB(hs + 1, (hs + 1) & 1);
      LOADA(hs + 1, (hs + 1) & 1);
    }
    DOMFMA(hs, hs & 1);
  }
#undef LOADB
#undef LOADA
#undef DOMFMA

  // ---- GRU epilogue: wave w writes features 16w..16w+15 of this block's
  // rows only; A was consumed from the LDS snapshot -> no barrier needed.
  const int c = w * 16 + lrow;            // feature 0..127
  const float br = bih[c] + bhh[c];
  const float bz = bih[128 + c] + bhh[128 + c];
  const float bni = bih[256 + c], bnh = bhh[256 + c];
  const size_t plane = (size_t)(w >> 1) * N;
  const int fidx = (w & 1) * 16 + lrow;

#pragma unroll
  for (int t = 0; t < 4; ++t) {
    const int rb = row0 + t * 16 + kq * 4;
#pragma unroll
    for (int i = 0; i < 4; ++i) {
      const int r = rb + i;
      if (r < N) {
        const float c1r = acc[(t * 3 + 0) * 2 + 0][i], c2r = acc[(t * 3 + 0) * 2 + 1][i];
        const float c1z = acc[(t * 3 + 1) * 2 + 0][i], c2z = acc[(t * 3 + 1) * 2 + 1][i];
        const float c1n = acc[(t * 3 + 2) * 2 + 0][i], c2n = acc[(t * 3 + 2) * 2 + 1][i];
        const float rr = 1.f / (1.f + __expf(-(c1r + c2r + br)));
        const float zz = 1.f / (1.f + __expf(-(c1z + c2z + bz)));
        const float nn = tanhf(c1n + bni + rr * (c2n + bnh));
        const size_t o = (plane + r) * 32 + fidx;
        const float hold = bf16f(h_hi_out[o]) + bf16f(h_lo_out[o]);
        const float hn = (1.f - zz) * nn + zz * hold;
        const unsigned short x = bf16_rne(hn);
        h_hi_out[o] = x;
        h_lo_out[o] = bf16_rne(hn - bf16f(x));
      }
    }
  }
}

// ---------------------------------------------------------------------------
// final: out[n] = relu(h[n]) . lin_w + lin_b
// ---------------------------------------------------------------------------
__global__ void final_kernel(const unsigned* __restrict__ hh, const unsigned* __restrict__ hl,
                             const float* __restrict__ lin_w,
                             const float* __restrict__ lin_b, float* __restrict__ out, int N) {
  int n = blockIdx.x * 4 + (threadIdx.x >> 6);
  if (n >= N) return;
  int d = threadIdx.x & 63;
  size_t o = ((size_t)(d >> 4) * N + n) * 16 + (d & 15);
  unsigned wh = hh[o], wl = hl[o];
  float v0 = bf16f((unsigned short)(wh & 0xffff)) + bf16f((unsigned short)(wl & 0xffff));
  float v1 = bf16f((unsigned short)(wh >> 16)) + bf16f((unsigned short)(wl >> 16));
  int f0 = (d >> 4) * 32 + 2 * (d & 15);
  float sum = fmaxf(v0, 0.f) * lin_w[f0] + fmaxf(v1, 0.f) * lin_w[f0 + 1];
#pragma unroll
  for (int s = 32; s; s >>= 1) sum += __shfl_xor(sum, s, 64);
  if (d == 0) out[n] = sum + lin_b[0];
}

// ---------------------------------------------------------------------------
extern "C" void kernel_launch(void* const* d_in, const int* in_sizes, int n_in,
                              void* d_out, int out_size, void* d_ws, size_t ws_size,
                              hipStream_t stream) {
  const float* x     = (const float*)d_in[0];
  const int*   ei    = (const int*)d_in[1];
  const float* W     = (const float*)d_in[2];
  const float* w_ih  = (const float*)d_in[3];
  const float* w_hh  = (const float*)d_in[4];
  const float* b_ih  = (const float*)d_in[5];
  const float* b_hh  = (const float*)d_in[6];
  const float* lin_w = (const float*)d_in[7];
  const float* lin_b = (const float*)d_in[8];

  const int N = in_sizes[0] / F;
  const int E = in_sizes[1] / 2;
  const int L = in_sizes[2] / (F * F);
  const size_t NF = (size_t)N * F;

  char* p = (char*)d_ws;
  unsigned short* h_hi = (unsigned short*)p; p += NF * 2;
  unsigned short* h_lo = (unsigned short*)p; p += NF * 2;
  unsigned short* s_hi = (unsigned short*)p; p += NF * 2;
  unsigned short* s_lo = (unsigned short*)p; p += NF * 2;
  unsigned short* Bpack = (unsigned short*)p; p += (size_t)L * 196608 * 2;
  int* cnt     = (int*)p; p += (size_t)N * 4;
  int* exscan  = (int*)p; p += (size_t)N * 4;
  int* chunk   = (int*)p; p += 256 * 4;
  int* rowptr  = (int*)p; p += ((size_t)N + 1) * 4;
  int* cursor  = (int*)p; p += (size_t)N * 4;
  int* csr_src = (int*)p; p += (size_t)E * 4;

  const int split_blocks = (N * 16 + 255) / 256;
  const int prep_blocks = (L * 98304 + 255) / 256;
  const int edge_blocks = (E + 255) / 256;
  const int nchunk = (N + 255) / 256;
  const int gemm_blocks = (N + 63) / 64;
  const int node4_blocks = (N + 3) / 4;

  split8_kernel<<<split_blocks, 256, 0, stream>>>(x, h_hi, h_lo, N);
  prep_w_kernel<<<prep_blocks, 256, 0, stream>>>(W, w_ih, w_hh, Bpack, L);

  hipMemsetAsync(cnt, 0, (size_t)N * 4, stream);
  hist_kernel<<<edge_blocks, 256, 0, stream>>>(ei, cnt, E);
  scan1_kernel<<<nchunk, 256, 0, stream>>>(cnt, exscan, chunk, N);
  scan2_kernel<<<1, 256, 0, stream>>>(chunk, nchunk);
  finalize_rowptr_kernel<<<(N + 256) / 256, 256, 0, stream>>>(exscan, chunk, rowptr, cursor, N, E);
  place_kernel<<<edge_blocks, 256, 0, stream>>>(ei, cursor, csr_src, E);

  for (int t = 0; t < L; ++t) {
    gather_kernel<<<node4_blocks, 256, 0, stream>>>(
        (const unsigned*)h_hi, (const unsigned*)h_lo, rowptr, csr_src,
        (unsigned*)s_hi, (unsigned*)s_lo, N);
    gemm_gru_kernel<<<gemm_blocks, 512, 0, stream>>>(
        s_hi, s_lo, h_hi, h_lo, Bpack + (size_t)t * 196608,
        b_ih, b_hh, h_hi, h_lo, N);
  }

  final_kernel<<<node4_blocks, 256, 0, stream>>>(
      (const unsigned*)h_hi, (const unsigned*)h_lo, lin_w, lin_b, (float*)d_out, N);
}

// Round 6
// 673.916 us; speedup vs baseline: 1.4534x; 1.2586x over previous
//
#include <hip/hip_runtime.h>

typedef float f32x4 __attribute__((ext_vector_type(4)));
typedef __bf16 bf16x8 __attribute__((ext_vector_type(8)));
typedef unsigned short u16x8 __attribute__((ext_vector_type(8)));

#define F 128

__device__ __forceinline__ unsigned short bf16_rne(float f) {
  unsigned u = __float_as_uint(f);
  u += 0x7FFFu + ((u >> 16) & 1u);
  return (unsigned short)(u >> 16);
}
__device__ __forceinline__ float bf16f(unsigned short s) {
  return __uint_as_float((unsigned)s << 16);
}

// Activation layout: ROW-MAJOR [node][128] u16 (hi and lo arrays).
// Weight layout FRAG-PACKED: per layer, frag ff = ((ks*2+g)*8 + w)*3 + part,
// storage [ff][hi 1KB][lo 1KB]; frag byte l*16+e*2 holds
// B[part*128 + w*16 + (l&15)][ks*32 + (l>>4)*8 + e].  g=0: Wc, g=1: Whh.

// ---------------------------------------------------------------------------
// split8: x (f32, row-major) -> row-major bf16 hi/lo
// ---------------------------------------------------------------------------
__global__ void split8_kernel(const float* __restrict__ in,
                              unsigned short* __restrict__ hi, unsigned short* __restrict__ lo,
                              int N) {
  int i = blockIdx.x * 256 + threadIdx.x;  // over N*16
  if (i >= N * 16) return;
  int node = i >> 4, f8 = i & 15;
  const float4* p = (const float4*)(in + (size_t)node * F + f8 * 8);
  float4 a = p[0], b = p[1];
  float v[8] = {a.x, a.y, a.z, a.w, b.x, b.y, b.z, b.w};
  u16x8 vh, vl;
#pragma unroll
  for (int e = 0; e < 8; ++e) {
    unsigned short x = bf16_rne(v[e]);
    vh[e] = x;
    vl[e] = bf16_rne(v[e] - bf16f(x));
  }
  size_t o = (size_t)node * F + f8 * 8;
  *(u16x8*)(hi + o) = vh;
  *(u16x8*)(lo + o) = vl;
}

// ---------------------------------------------------------------------------
// prep_w: frag-packed combined weights.
//   Wc[t][j][k] = dot(W[t][k][:], w_ih[j][:]);  Whh[j][k] = w_hh[j][k]
// ---------------------------------------------------------------------------
__global__ void prep_w_kernel(const float* __restrict__ W, const float* __restrict__ w_ih,
                              const float* __restrict__ w_hh,
                              unsigned short* __restrict__ Bpack, int L) {
  int idx = blockIdx.x * 256 + threadIdx.x;
  if (idx >= L * 98304) return;
  int e = idx & 7;
  int l = (idx >> 3) & 63;
  int fp = idx >> 9;            // frag-value group: L*192
  int part = fp % 3;
  int rest = fp / 3;            // L*64
  int w = rest & 7, g = (rest >> 3) & 1, ks = (rest >> 4) & 3, t = rest >> 6;
  int j = part * 128 + w * 16 + (l & 15);
  int k = ks * 32 + ((l >> 4) & 3) * 8 + e;
  float v;
  if (g == 0) {
    const float* wi = w_ih + (size_t)j * 128;
    const float* wk = W + (size_t)t * 16384 + (size_t)k * 128;
    float acc = 0.f;
#pragma unroll 4
    for (int c = 0; c < 128; ++c) acc = fmaf(wk[c], wi[c], acc);
    v = acc;
  } else {
    v = w_hh[(size_t)j * 128 + k];
  }
  int ff = ((ks * 2 + g) * 8 + w) * 3 + part;
  size_t base = (size_t)t * 196608 + (size_t)ff * 1024 + l * 8 + e;
  unsigned short x = bf16_rne(v);
  Bpack[base] = x;
  Bpack[base + 512] = bf16_rne(v - bf16f(x));
}

// ---------------------------------------------------------------------------
// CSR build
// ---------------------------------------------------------------------------
__global__ void hist_kernel(const int* __restrict__ ei, int* __restrict__ cnt, int E) {
  int e = blockIdx.x * 256 + threadIdx.x;
  if (e < E) atomicAdd(&cnt[ei[E + e]], 1);
}

__global__ void scan1_kernel(const int* __restrict__ cnt, int* __restrict__ exscan,
                             int* __restrict__ chunk_sums, int N) {
  __shared__ int tmp[256];
  int i = blockIdx.x * 256 + threadIdx.x;
  int v = (i < N) ? cnt[i] : 0;
  tmp[threadIdx.x] = v;
  __syncthreads();
#pragma unroll
  for (int off = 1; off < 256; off <<= 1) {
    int a = (threadIdx.x >= off) ? tmp[threadIdx.x - off] : 0;
    __syncthreads();
    tmp[threadIdx.x] += a;
    __syncthreads();
  }
  if (i < N) exscan[i] = tmp[threadIdx.x] - v;
  if (threadIdx.x == 255) chunk_sums[blockIdx.x] = tmp[255];
}

__global__ void scan2_kernel(int* __restrict__ chunk_sums, int nchunk) {
  __shared__ int tmp[256];
  int v = (threadIdx.x < nchunk) ? chunk_sums[threadIdx.x] : 0;
  tmp[threadIdx.x] = v;
  __syncthreads();
#pragma unroll
  for (int off = 1; off < 256; off <<= 1) {
    int a = (threadIdx.x >= off) ? tmp[threadIdx.x - off] : 0;
    __syncthreads();
    tmp[threadIdx.x] += a;
    __syncthreads();
  }
  if (threadIdx.x < nchunk) chunk_sums[threadIdx.x] = tmp[threadIdx.x] - v;
}

__global__ void finalize_rowptr_kernel(const int* __restrict__ exscan,
                                       const int* __restrict__ chunk_sums,
                                       int* __restrict__ rowptr, int* __restrict__ cursor,
                                       int N, int E) {
  int i = blockIdx.x * 256 + threadIdx.x;
  if (i < N) {
    int v = exscan[i] + chunk_sums[i >> 8];
    rowptr[i] = v;
    cursor[i] = v;
  }
  if (i == N) rowptr[N] = E;
}

__global__ void place_kernel(const int* __restrict__ ei, int* __restrict__ cursor,
                             int* __restrict__ csr_src, int E) {
  int e = blockIdx.x * 256 + threadIdx.x;
  if (e >= E) return;
  int pos = atomicAdd(&cursor[ei[E + e]], 1);
  csr_src[pos] = ei[e];
}

// ---------------------------------------------------------------------------
// gather: one wave per node. Lane group grp = lane>>4:
//   grp0: hh edge-parity0, grp1: hl p0, grp2: hh p1, grp3: hl p1.
// Per edge-pair each lane loads one uint4 (16B, 8 features) -> each edge's
// 512B is read as 4 full 128B lines in 32 wide loads. Combine via shfl_xor.
// ---------------------------------------------------------------------------
__global__ __launch_bounds__(256) void gather_kernel(
    const unsigned short* __restrict__ hh, const unsigned short* __restrict__ hl,
    const int* __restrict__ rowptr, const int* __restrict__ csr_src,
    unsigned short* __restrict__ shi, unsigned short* __restrict__ slo, int N) {
  int node = blockIdx.x * 4 + (threadIdx.x >> 6);
  if (node >= N) return;
  const int lane = threadIdx.x & 63;
  const int grp = lane >> 4, sub = lane & 15;
  const int par = grp >> 1;
  const unsigned short* base = (grp & 1) ? hl : hh;
  const int beg = rowptr[node], end = rowptr[node + 1];
  float a[8] = {0.f, 0.f, 0.f, 0.f, 0.f, 0.f, 0.f, 0.f};
  int j = beg;
  for (; j + 4 <= end; j += 4) {  // 4 edges per iter, 2 loads per lane
    int e0 = csr_src[j + par];
    int e1 = csr_src[j + 2 + par];
    u16x8 v0 = *(const u16x8*)(base + (size_t)e0 * F + sub * 8);
    u16x8 v1 = *(const u16x8*)(base + (size_t)e1 * F + sub * 8);
#pragma unroll
    for (int q = 0; q < 8; ++q) a[q] += bf16f(v0[q]) + bf16f(v1[q]);
  }
  if (j + 2 <= end) {  // 2 edges
    int e0 = csr_src[j + par];
    u16x8 v0 = *(const u16x8*)(base + (size_t)e0 * F + sub * 8);
#pragma unroll
    for (int q = 0; q < 8; ++q) a[q] += bf16f(v0[q]);
    j += 2;
  }
  if (j < end && par == 0) {  // last single edge: only parity-0 groups
    int e0 = csr_src[j];
    u16x8 v0 = *(const u16x8*)(base + (size_t)e0 * F + sub * 8);
#pragma unroll
    for (int q = 0; q < 8; ++q) a[q] += bf16f(v0[q]);
  }
#pragma unroll
  for (int q = 0; q < 8; ++q) {
    a[q] += __shfl_xor(a[q], 32, 64);  // combine edge parities
    a[q] += __shfl_xor(a[q], 16, 64);  // combine hi + lo contributions
  }
  if (grp == 0) {
    u16x8 o;
#pragma unroll
    for (int q = 0; q < 8; ++q) o[q] = bf16_rne(a[q]);
    *(u16x8*)(shi + (size_t)node * F + sub * 8) = o;
  } else if (grp == 1) {
    u16x8 o;
#pragma unroll
    for (int q = 0; q < 8; ++q) {
      unsigned short x = bf16_rne(a[q]);
      o[q] = bf16_rne(a[q] - bf16f(x));
    }
    *(u16x8*)(slo + (size_t)node * F + sub * 8) = o;
  }
}

// ---------------------------------------------------------------------------
// gemm_gru: 64 rows x 384 gate-cols per block, 8 waves. Wave w owns feature
// tile w (16 features) = coltiles {r,z,n} for all 64 rows -> B loaded once
// per block. A (s,h hi/lo) staged once into 64KB LDS via global_load_lds
// (row-major source, per-lane addresses; linear LDS dest); ONE barrier.
// K-loop: 8 half-steps hs = ks*2+g; 2-deep register double-buffer.
// ---------------------------------------------------------------------------
__device__ __forceinline__ void g2l(const void* g, void* l) {
  __builtin_amdgcn_global_load_lds((const __attribute__((address_space(1))) void*)g,
                                   (__attribute__((address_space(3))) void*)l, 16, 0, 0);
}

__global__ __launch_bounds__(512, 2) void gemm_gru_kernel(
    const unsigned short* __restrict__ s_hi, const unsigned short* __restrict__ s_lo,
    const unsigned short* __restrict__ h_hi, const unsigned short* __restrict__ h_lo,
    const unsigned short* __restrict__ Bpack,
    const float* __restrict__ bih, const float* __restrict__ bhh,
    unsigned short* h_hi_out, unsigned short* h_lo_out, int N) {
  __shared__ __align__(1024) unsigned char lds[65536];
  const int tid = threadIdx.x, w = tid >> 6, lane = tid & 63;
  const int lrow = lane & 15, kq = lane >> 4;
  const int row0 = blockIdx.x * 64;

  // ---- stage A: 64 x 1KB chunks; chunk ci = w*8 + i covers
  //      (array = ci>>4, ks = (ci>>2)&3, quarter = ci&3), rows quarter*16..+15
  {
    const int arr = w >> 1;  // wave-constant
    const unsigned short* ap = (arr == 0) ? s_hi : (arr == 1) ? s_lo : (arr == 2) ? h_hi : h_lo;
#pragma unroll
    for (int i = 0; i < 8; ++i) {
      const int ks = (2 * w + (i >> 2)) & 3;
      int r = row0 + (i & 3) * 16 + (lane >> 2);
      if (r >= N) r = N - 1;
      const unsigned short* g = ap + (size_t)r * F + ks * 32 + (lane & 3) * 8;
      g2l(g, lds + (w * 8 + i) * 1024 + lane * 16);
    }
  }

  f32x4 acc[24];  // [(t*3+part)*2 + g]
#pragma unroll
  for (int i = 0; i < 24; ++i) acc[i] = (f32x4){0.f, 0.f, 0.f, 0.f};

  bf16x8 Bf[2][6];  // [buf][part*2 + hl]
  bf16x8 Af[2][8];  // [buf][t] = hi, [buf][4+t] = lo

  const unsigned char* Bbase = (const unsigned char*)Bpack + (size_t)w * 6144 + lane * 16;

  asm volatile("s_waitcnt vmcnt(0)" ::: "memory");
  __syncthreads();

#define LOADB(hs, buf)                                                           \
  {                                                                              \
    const unsigned char* bg = Bbase + (size_t)(hs) * 49152;                      \
    _Pragma("unroll") for (int i = 0; i < 6; ++i)                                \
        Bf[buf][i] = *(const bf16x8*)(bg + i * 1024);                            \
  }
#define LOADA(hs, buf)                                                           \
  {                                                                              \
    const int ks_ = (hs) >> 1, g_ = (hs) & 1;                                    \
    const unsigned char* bh = lds + ((g_ * 2) * 4 + ks_) * 4096 + lrow * 64 + kq * 16;      \
    const unsigned char* bl = lds + ((g_ * 2 + 1) * 4 + ks_) * 4096 + lrow * 64 + kq * 16;  \
    _Pragma("unroll") for (int t = 0; t < 4; ++t) {                              \
      Af[buf][t] = *(const bf16x8*)(bh + t * 1024);                              \
      Af[buf][4 + t] = *(const bf16x8*)(bl + t * 1024);                          \
    }                                                                            \
  }
#define DOMFMA(hs, buf)                                                          \
  {                                                                              \
    const int g_ = (hs) & 1;                                                     \
    _Pragma("unroll") for (int part = 0; part < 3; ++part)                       \
        _Pragma("unroll") for (int t = 0; t < 4; ++t) {                          \
      const int ai = (t * 3 + part) * 2 + g_;                                    \
      acc[ai] = __builtin_amdgcn_mfma_f32_16x16x32_bf16(Af[buf][t], Bf[buf][part * 2], acc[ai], 0, 0, 0);     \
      acc[ai] = __builtin_amdgcn_mfma_f32_16x16x32_bf16(Af[buf][4 + t], Bf[buf][part * 2], acc[ai], 0, 0, 0); \
      acc[ai] = __builtin_amdgcn_mfma_f32_16x16x32_bf16(Af[buf][t], Bf[buf][part * 2 + 1], acc[ai], 0, 0, 0); \
    }                                                                            \
  }

  LOADB(0, 0);
  LOADA(0, 0);
#pragma unroll
  for (int hs = 0; hs < 8; ++hs) {
    if (hs < 7) {
      LOADB(hs + 1, (hs + 1) & 1);
      LOADA(hs + 1, (hs + 1) & 1);
    }
    DOMFMA(hs, hs & 1);
  }
#undef LOADB
#undef LOADA
#undef DOMFMA

  // ---- GRU epilogue: wave w writes features 16w..16w+15 of this block's
  // rows only; A was consumed from the LDS snapshot -> no barrier needed.
  const int c = w * 16 + lrow;  // feature 0..127
  const float br = bih[c] + bhh[c];
  const float bz = bih[128 + c] + bhh[128 + c];
  const float bni = bih[256 + c], bnh = bhh[256 + c];

#pragma unroll
  for (int t = 0; t < 4; ++t) {
    const int rb = row0 + t * 16 + kq * 4;
#pragma unroll
    for (int i = 0; i < 4; ++i) {
      const int r = rb + i;
      if (r < N) {
        const float c1r = acc[(t * 3 + 0) * 2 + 0][i], c2r = acc[(t * 3 + 0) * 2 + 1][i];
        const float c1z = acc[(t * 3 + 1) * 2 + 0][i], c2z = acc[(t * 3 + 1) * 2 + 1][i];
        const float c1n = acc[(t * 3 + 2) * 2 + 0][i], c2n = acc[(t * 3 + 2) * 2 + 1][i];
        const float rr = 1.f / (1.f + __expf(-(c1r + c2r + br)));
        const float zz = 1.f / (1.f + __expf(-(c1z + c2z + bz)));
        const float nn = tanhf(c1n + bni + rr * (c2n + bnh));
        const size_t o = (size_t)r * F + c;
        const float hold = bf16f(h_hi_out[o]) + bf16f(h_lo_out[o]);
        const float hn = (1.f - zz) * nn + zz * hold;
        const unsigned short x = bf16_rne(hn);
        h_hi_out[o] = x;
        h_lo_out[o] = bf16_rne(hn - bf16f(x));
      }
    }
  }
}

// ---------------------------------------------------------------------------
// final: out[n] = relu(h[n]) . lin_w + lin_b
// ---------------------------------------------------------------------------
__global__ void final_kernel(const unsigned* __restrict__ hh, const unsigned* __restrict__ hl,
                             const float* __restrict__ lin_w,
                             const float* __restrict__ lin_b, float* __restrict__ out, int N) {
  int n = blockIdx.x * 4 + (threadIdx.x >> 6);
  if (n >= N) return;
  int d = threadIdx.x & 63;
  size_t o = (size_t)n * 64 + d;  // u32 view of row-major [node][128] u16
  unsigned wh = hh[o], wl = hl[o];
  float v0 = bf16f((unsigned short)(wh & 0xffff)) + bf16f((unsigned short)(wl & 0xffff));
  float v1 = bf16f((unsigned short)(wh >> 16)) + bf16f((unsigned short)(wl >> 16));
  float sum = fmaxf(v0, 0.f) * lin_w[2 * d] + fmaxf(v1, 0.f) * lin_w[2 * d + 1];
#pragma unroll
  for (int s = 32; s; s >>= 1) sum += __shfl_xor(sum, s, 64);
  if (d == 0) out[n] = sum + lin_b[0];
}

// ---------------------------------------------------------------------------
extern "C" void kernel_launch(void* const* d_in, const int* in_sizes, int n_in,
                              void* d_out, int out_size, void* d_ws, size_t ws_size,
                              hipStream_t stream) {
  const float* x     = (const float*)d_in[0];
  const int*   ei    = (const int*)d_in[1];
  const float* W     = (const float*)d_in[2];
  const float* w_ih  = (const float*)d_in[3];
  const float* w_hh  = (const float*)d_in[4];
  const float* b_ih  = (const float*)d_in[5];
  const float* b_hh  = (const float*)d_in[6];
  const float* lin_w = (const float*)d_in[7];
  const float* lin_b = (const float*)d_in[8];

  const int N = in_sizes[0] / F;
  const int E = in_sizes[1] / 2;
  const int L = in_sizes[2] / (F * F);
  const size_t NF = (size_t)N * F;

  char* p = (char*)d_ws;
  unsigned short* h_hi = (unsigned short*)p; p += NF * 2;
  unsigned short* h_lo = (unsigned short*)p; p += NF * 2;
  unsigned short* s_hi = (unsigned short*)p; p += NF * 2;
  unsigned short* s_lo = (unsigned short*)p; p += NF * 2;
  unsigned short* Bpack = (unsigned short*)p; p += (size_t)L * 196608 * 2;
  int* cnt     = (int*)p; p += (size_t)N * 4;
  int* exscan  = (int*)p; p += (size_t)N * 4;
  int* chunk   = (int*)p; p += 256 * 4;
  int* rowptr  = (int*)p; p += ((size_t)N + 1) * 4;
  int* cursor  = (int*)p; p += (size_t)N * 4;
  int* csr_src = (int*)p; p += (size_t)E * 4;

  const int split_blocks = (N * 16 + 255) / 256;
  const int prep_blocks = (L * 98304 + 255) / 256;
  const int edge_blocks = (E + 255) / 256;
  const int nchunk = (N + 255) / 256;
  const int gemm_blocks = (N + 63) / 64;
  const int node4_blocks = (N + 3) / 4;

  split8_kernel<<<split_blocks, 256, 0, stream>>>(x, h_hi, h_lo, N);
  prep_w_kernel<<<prep_blocks, 256, 0, stream>>>(W, w_ih, w_hh, Bpack, L);

  hipMemsetAsync(cnt, 0, (size_t)N * 4, stream);
  hist_kernel<<<edge_blocks, 256, 0, stream>>>(ei, cnt, E);
  scan1_kernel<<<nchunk, 256, 0, stream>>>(cnt, exscan, chunk, N);
  scan2_kernel<<<1, 256, 0, stream>>>(chunk, nchunk);
  finalize_rowptr_kernel<<<(N + 256) / 256, 256, 0, stream>>>(exscan, chunk, rowptr, cursor, N, E);
  place_kernel<<<edge_blocks, 256, 0, stream>>>(ei, cursor, csr_src, E);

  for (int t = 0; t < L; ++t) {
    gather_kernel<<<node4_blocks, 256, 0, stream>>>(
        h_hi, h_lo, rowptr, csr_src, s_hi, s_lo, N);
    gemm_gru_kernel<<<gemm_blocks, 512, 0, stream>>>(
        s_hi, s_lo, h_hi, h_lo, Bpack + (size_t)t * 196608,
        b_ih, b_hh, h_hi, h_lo, N);
  }

  final_kernel<<<node4_blocks, 256, 0, stream>>>(
      (const unsigned*)h_hi, (const unsigned*)h_lo, lin_w, lin_b, (float*)d_out, N);
}